// Round 10
// baseline (295.855 us; speedup 1.0000x reference)
//
#include <hip/hip_runtime.h>
#include <hip/hip_bf16.h>

#define N_NODES 100000
#define IN_DIM 128
#define OUT_DIM 32
#define NEG_SLOPE 0.01f
#define E_DEFAULT 1600000
#define BUCKET_SHIFT 7
#define BUCKET_SIZE 128
#define NB ((N_NODES + BUCKET_SIZE - 1) / BUCKET_SIZE)   // 782
#define ECHUNK 1024
#define PCAP 8192
#define WPAD 136   // bf16 LDS row stride for fc_w (16B-aligned, bank-balanced)

typedef __attribute__((ext_vector_type(8))) short bf16x8;
typedef __attribute__((ext_vector_type(4))) float f32x4;

__device__ __forceinline__ float bfu2f(unsigned int u16) {
    union { unsigned int i; float f; } v;
    v.i = u16 << 16;
    return v.f;
}
__device__ __forceinline__ unsigned short f2bfu(float f) {
    union { unsigned int i; float f; } v;
    v.f = f;
    unsigned int r = v.i + 0x7fffu + ((v.i >> 16) & 1u);  // RNE
    return (unsigned short)(r >> 16);
}

// K1 (MFMA z/scores + LDS-hist -> bsum atomics; no blkcnt matrix).
// One wave = 16 nodes x 32 dims; block b also histograms edge chunk b.
__global__ __launch_bounds__(256) void k1_fused(
    const float* __restrict__ h,
    const float* __restrict__ fc_w,
    const float* __restrict__ attn_w,
    const int* __restrict__ dst,
    unsigned short* __restrict__ zbf,
    float* __restrict__ s_l,
    float* __restrict__ s_r,
    int* __restrict__ bsum,
    int E, int nblk) {
    __shared__ unsigned short wlds[OUT_DIM * WPAD];  // 8.5 KB bf16
    __shared__ float al[OUT_DIM], ar[OUT_DIM];
    __shared__ int bins[NB];

    const int t = threadIdx.x;
    for (int i = t; i < NB; i += 256) bins[i] = 0;
    for (int i = t; i < OUT_DIM * IN_DIM / 4; i += 256) {
        const float4 v = ((const float4*)fc_w)[i];
        const int idx = i * 4;
        const int row = idx >> 7, col = idx & 127;
        unsigned short* p = &wlds[row * WPAD + col];
        p[0] = f2bfu(v.x); p[1] = f2bfu(v.y); p[2] = f2bfu(v.z); p[3] = f2bfu(v.w);
    }
    if (t < 2 * OUT_DIM) {
        if (t < OUT_DIM) al[t] = attn_w[t];
        else ar[t - OUT_DIM] = attn_w[t];
    }
    __syncthreads();

    // fused histogram of this block's edge chunk (LDS bins)
    if (blockIdx.x < nblk) {
        const int e0 = blockIdx.x * ECHUNK;
#pragma unroll
        for (int k = 0; k < ECHUNK; k += 256) {
            const int e = e0 + k + t;
            if (e < E) atomicAdd(&bins[dst[e] >> BUCKET_SHIFT], 1);
        }
    }

    // MFMA z + scores
    const int wid = blockIdx.x * 4 + (t >> 6);
    int base = wid * 16;
    if (base > N_NODES - 16) base = N_NODES - 16;   // clamp: duplicates benign
    const int lane = t & 63;
    const int row16 = lane & 15;
    const int quad = lane >> 4;

    f32x4 acc0 = {0.f, 0.f, 0.f, 0.f};
    f32x4 acc1 = {0.f, 0.f, 0.f, 0.f};
    const float* hrow = h + (size_t)(base + row16) * IN_DIM + quad * 8;
    const unsigned short* b0 = &wlds[row16 * WPAD + quad * 8];
    const unsigned short* b1 = &wlds[(row16 + 16) * WPAD + quad * 8];

#pragma unroll
    for (int s = 0; s < 4; ++s) {
        const float4 a0 = *(const float4*)(hrow + s * 32);
        const float4 a1 = *(const float4*)(hrow + s * 32 + 4);
        bf16x8 af;
        af[0] = (short)f2bfu(a0.x); af[1] = (short)f2bfu(a0.y);
        af[2] = (short)f2bfu(a0.z); af[3] = (short)f2bfu(a0.w);
        af[4] = (short)f2bfu(a1.x); af[5] = (short)f2bfu(a1.y);
        af[6] = (short)f2bfu(a1.z); af[7] = (short)f2bfu(a1.w);
        const bf16x8 bf0 = *(const bf16x8*)(b0 + s * 32);
        const bf16x8 bf1 = *(const bf16x8*)(b1 + s * 32);
        acc0 = __builtin_amdgcn_mfma_f32_16x16x32_bf16(af, bf0, acc0, 0, 0, 0);
        acc1 = __builtin_amdgcn_mfma_f32_16x16x32_bf16(af, bf1, acc1, 0, 0, 0);
    }

    const float al_lo = al[row16], al_hi = al[row16 + 16];
    const float ar_lo = ar[row16], ar_hi = ar[row16 + 16];
#pragma unroll
    for (int r = 0; r < 4; ++r) {
        const int node = base + quad * 4 + r;
        float p = acc0[r] * al_lo + acc1[r] * al_hi;
        float q = acc0[r] * ar_lo + acc1[r] * ar_hi;
        p += __shfl_xor(p, 1, 64); p += __shfl_xor(p, 2, 64);
        p += __shfl_xor(p, 4, 64); p += __shfl_xor(p, 8, 64);
        q += __shfl_xor(q, 1, 64); q += __shfl_xor(q, 2, 64);
        q += __shfl_xor(q, 4, 64); q += __shfl_xor(q, 8, 64);
        if (row16 == 0) { s_l[node] = p; s_r[node] = q; }
        zbf[(size_t)node * OUT_DIM + row16] = f2bfu(acc0[r]);
        zbf[(size_t)node * OUT_DIM + 16 + row16] = f2bfu(acc1[r]);
    }

    __syncthreads();
    if (blockIdx.x < nblk) {
        for (int i = t; i < NB; i += 256) {
            const int c = bins[i];
            if (c) atomicAdd(&bsum[i], c);
        }
    }
}

// 1 block: exclusive scan over bucket totals -> bstart; init global cursors.
__global__ __launch_bounds__(1024) void k_scan_top(
    const int* __restrict__ bsum, int* __restrict__ bstart,
    int* __restrict__ cursor) {
    __shared__ int sc[1024];
    const int t = threadIdx.x;
    const int v = (t < NB) ? bsum[t] : 0;
    sc[t] = v;
    __syncthreads();
    for (int off = 1; off < 1024; off <<= 1) {
        const int u = (t >= off) ? sc[t - off] : 0;
        __syncthreads();
        sc[t] += u;
        __syncthreads();
    }
    if (t < NB) {
        const int st = sc[t] - v;
        bstart[t] = st;
        cursor[t] = st;
    }
    if (t == 1023) bstart[NB] = sc[1023];
}

// Two-pass scatter: LDS hist -> one global range-reservation atomic per
// nonzero bin -> LDS-cursor placement of packed {ldst:7|src:17}.
__global__ __launch_bounds__(256) void k_scatter3(
    const int* __restrict__ src, const int* __restrict__ dst,
    int* __restrict__ cursor, int* __restrict__ packed, int E) {
    __shared__ int bins[NB];
    __shared__ int basep[NB];
    const int t = threadIdx.x;
    for (int i = t; i < NB; i += 256) bins[i] = 0;
    __syncthreads();
    const int e0 = blockIdx.x * ECHUNK;
#pragma unroll
    for (int k = 0; k < ECHUNK; k += 256) {
        const int e = e0 + k + t;
        if (e < E) atomicAdd(&bins[dst[e] >> BUCKET_SHIFT], 1);
    }
    __syncthreads();
    for (int i = t; i < NB; i += 256) {
        const int c = bins[i];
        basep[i] = c ? atomicAdd(&cursor[i], c) : 0;
        bins[i] = 0;   // reuse as local cursor
    }
    __syncthreads();
#pragma unroll
    for (int k = 0; k < ECHUNK; k += 256) {
        const int e = e0 + k + t;
        if (e < E) {
            const int d = dst[e];
            const int bin = d >> BUCKET_SHIFT;
            const int pos = basep[bin] + atomicAdd(&bins[bin], 1);
            packed[pos] = ((d & (BUCKET_SIZE - 1)) << 17) | src[e];
        }
    }
}

// One block per bucket: LDS stage, per-node count + scan -> nstart, permute
// to node-sorted src, AND compute per-edge weight w = exp(lrelu(.)) once,
// stored bf16 (moves exp + random s_l load off gather's critical path).
__global__ __launch_bounds__(256) void k_place_w(
    const int* __restrict__ bstart,
    int* __restrict__ packed,
    int* __restrict__ nstart,
    const float* __restrict__ s_l,
    const float* __restrict__ s_r,
    unsigned short* __restrict__ wexp) {
    __shared__ int pk[PCAP];
    __shared__ int cnt128[BUCKET_SIZE];
    __shared__ int pref[BUCKET_SIZE];
    __shared__ int cur[BUCKET_SIZE];
    __shared__ float srt[BUCKET_SIZE];

    const int bin = blockIdx.x;
    const int base = bin * BUCKET_SIZE;
    const int st = bstart[bin];
    int cnt = bstart[bin + 1] - st;
    if (cnt > PCAP) cnt = PCAP;
    const int t = threadIdx.x;

    if (t < BUCKET_SIZE) {
        cnt128[t] = 0;
        const int n = base + t;
        srt[t] = (n < N_NODES) ? s_r[n] : 0.f;
    }
    __syncthreads();
    for (int i = t; i < cnt; i += 256) {
        const int p = packed[st + i];
        pk[i] = p;
        atomicAdd(&cnt128[p >> 17], 1);
    }
    __syncthreads();
    if (t < BUCKET_SIZE) pref[t] = cnt128[t];
    __syncthreads();
    for (int off = 1; off < BUCKET_SIZE; off <<= 1) {
        int u = 0;
        if (t < BUCKET_SIZE && t >= off) u = pref[t - off];
        __syncthreads();
        if (t < BUCKET_SIZE) pref[t] += u;
        __syncthreads();
    }
    if (t < BUCKET_SIZE) {
        const int excl = pref[t] - cnt128[t];
        nstart[base + t] = st + excl;
        cur[t] = excl;
    }
    __syncthreads();
    for (int i = t; i < cnt; i += 256) {
        const int p = pk[i];
        const int ldst = p >> 17;
        const int sn = p & 0x1FFFF;
        const int pos = st + atomicAdd(&cur[ldst], 1);
        float x = s_l[sn] + srt[ldst];
        x = (x > 0.f) ? x : NEG_SLOPE * x;
        packed[pos] = sn;
        wexp[pos] = f2bfu(__expf(x));
    }
}

// One wave per node: 8 edge streams x 8 dim-groups. No exp, no s_l — weight
// preloaded bf16. Chain: nstart -> (packed,wexp) -> zbf.
__global__ __launch_bounds__(256) void k_gather8w(
    const int* __restrict__ nstart,
    const int* __restrict__ esrc,
    const unsigned short* __restrict__ wexp,
    const unsigned short* __restrict__ zbf,
    float* __restrict__ out) {
    const int gtid = blockIdx.x * 256 + threadIdx.x;
    const int n = gtid >> 6;
    if (n >= N_NODES) return;
    const int lane = gtid & 63;
    const int eslot = lane >> 3;
    const int dimg = lane & 7;

    const int st = nstart[n];
    const int cnt = nstart[n + 1] - st;

    float a0 = 0.f, a1 = 0.f, a2 = 0.f, a3 = 0.f, dn = 0.f;
    for (int i = eslot; i < cnt; i += 8) {
        const int es = esrc[st + i];
        const float w = bfu2f(wexp[st + i]);
        const uint2 zv = *(const uint2*)&zbf[(size_t)es * OUT_DIM + dimg * 4];
        a0 += w * bfu2f(zv.x & 0xffffu);
        a1 += w * bfu2f(zv.x >> 16);
        a2 += w * bfu2f(zv.y & 0xffffu);
        a3 += w * bfu2f(zv.y >> 16);
        dn += w;
    }
#pragma unroll
    for (int m = 8; m < 64; m <<= 1) {
        a0 += __shfl_xor(a0, m, 64);
        a1 += __shfl_xor(a1, m, 64);
        a2 += __shfl_xor(a2, m, 64);
        a3 += __shfl_xor(a3, m, 64);
        dn += __shfl_xor(dn, m, 64);
    }
    if (eslot == 0) {
        const float inv = (dn > 0.f) ? 1.f / dn : 0.f;
        *(float4*)&out[(size_t)n * OUT_DIM + dimg * 4] =
            make_float4(a0 * inv, a1 * inv, a2 * inv, a3 * inv);
    }
}

// ---------------- atomic fallback path (known-passing) ----------

__global__ __launch_bounds__(256) void k1_z_scores(
    const float* __restrict__ h,
    const float* __restrict__ fc_w,
    const float* __restrict__ attn_w,
    unsigned short* __restrict__ zbf,
    float* __restrict__ s_l,
    float* __restrict__ s_r,
    float* __restrict__ denom,
    float* __restrict__ out) {
    __shared__ float wlds[OUT_DIM * IN_DIM];
    __shared__ float al[OUT_DIM], ar[OUT_DIM];

    const int tid = threadIdx.x;
    for (int i = tid; i < OUT_DIM * IN_DIM; i += 256) wlds[i] = fc_w[i];
    if (tid < OUT_DIM) {
        al[tid] = attn_w[tid];
        ar[tid] = attn_w[OUT_DIM + tid];
    }
    __syncthreads();

    const int node = blockIdx.x * 256 + tid;
    if (node >= N_NODES) return;

    float acc[OUT_DIM];
#pragma unroll
    for (int j = 0; j < OUT_DIM; ++j) acc[j] = 0.f;
    const float4* hp = (const float4*)(h + (size_t)node * IN_DIM);
#pragma unroll 4
    for (int kg = 0; kg < IN_DIM / 4; ++kg) {
        const float4 hv = hp[kg];
#pragma unroll
        for (int j = 0; j < OUT_DIM; ++j) {
            const float4 w = *(const float4*)&wlds[j * IN_DIM + kg * 4];
            acc[j] += hv.x * w.x + hv.y * w.y + hv.z * w.z + hv.w * w.w;
        }
    }
    float sl = 0.f, sr = 0.f;
#pragma unroll
    for (int j = 0; j < OUT_DIM; ++j) { sl += acc[j] * al[j]; sr += acc[j] * ar[j]; }
    s_l[node] = sl; s_r[node] = sr; denom[node] = 0.f;
    uint4* zp = (uint4*)(zbf + (size_t)node * OUT_DIM);
#pragma unroll
    for (int q = 0; q < 4; ++q) {
        uint4 pk;
        pk.x = (unsigned int)f2bfu(acc[8 * q + 0]) | ((unsigned int)f2bfu(acc[8 * q + 1]) << 16);
        pk.y = (unsigned int)f2bfu(acc[8 * q + 2]) | ((unsigned int)f2bfu(acc[8 * q + 3]) << 16);
        pk.z = (unsigned int)f2bfu(acc[8 * q + 4]) | ((unsigned int)f2bfu(acc[8 * q + 5]) << 16);
        pk.w = (unsigned int)f2bfu(acc[8 * q + 6]) | ((unsigned int)f2bfu(acc[8 * q + 7]) << 16);
        zp[q] = pk;
    }
    float4* op = (float4*)(out + (size_t)node * OUT_DIM);
    const float4 zero4 = make_float4(0.f, 0.f, 0.f, 0.f);
#pragma unroll
    for (int q = 0; q < 8; ++q) op[q] = zero4;
}

__global__ __launch_bounds__(256) void k3_edges(
    const int* __restrict__ src, const int* __restrict__ dst,
    const float* __restrict__ s_l, const float* __restrict__ s_r,
    const unsigned short* __restrict__ zbf,
    float* __restrict__ denom, float* __restrict__ out, int E) {
    const long long gid = (long long)blockIdx.x * 256 + threadIdx.x;
    const int e = (int)(gid >> 3);
    const int q = (int)(gid & 7);
    if (e >= E) return;
    const int s = src[e];
    const int d = dst[e];
    float x = s_l[s] + s_r[d];
    x = (x > 0.f) ? x : NEG_SLOPE * x;
    const float w = __expf(x);
    const uint2 zv = *(const uint2*)&zbf[(size_t)s * OUT_DIM + q * 4];
    float* op = &out[(size_t)d * OUT_DIM + q * 4];
    unsafeAtomicAdd(op + 0, w * bfu2f(zv.x & 0xffffu));
    unsafeAtomicAdd(op + 1, w * bfu2f(zv.x >> 16));
    unsafeAtomicAdd(op + 2, w * bfu2f(zv.y & 0xffffu));
    unsafeAtomicAdd(op + 3, w * bfu2f(zv.y >> 16));
    if (q == 0) unsafeAtomicAdd(&denom[d], w);
}

__global__ __launch_bounds__(256) void k4_finalize(
    const float* __restrict__ denom, float* __restrict__ out) {
    const int i = blockIdx.x * 256 + threadIdx.x;
    if (i >= N_NODES * OUT_DIM) return;
    const float dnm = denom[i >> 5];
    out[i] = (dnm > 0.f) ? out[i] / dnm : 0.f;
}

extern "C" void kernel_launch(void* const* d_in, const int* in_sizes, int n_in,
                              void* d_out, int out_size, void* d_ws, size_t ws_size,
                              hipStream_t stream) {
    const float* h      = (const float*)d_in[0];
    const int*   src    = (const int*)d_in[1];
    const int*   dst    = (const int*)d_in[2];
    const float* fc_w   = (const float*)d_in[3];
    const float* attn_w = (const float*)d_in[4];
    float* out = (float*)d_out;
    const int E = (in_sizes[1] > 0) ? in_sizes[1] : E_DEFAULT;
    const int nblk = (E + ECHUNK - 1) / ECHUNK;           // 1563

    char* ws = (char*)d_ws;
    size_t off = 0;
    unsigned short* zbf = (unsigned short*)(ws + off);
    off += (size_t)N_NODES * OUT_DIM * sizeof(unsigned short);       // 6.4 MB
    float* s_l = (float*)(ws + off); off += (size_t)N_NODES * 4;     // 0.4 MB
    float* s_r = (float*)(ws + off); off += (size_t)N_NODES * 4;     // 0.4 MB

    const size_t base = off;
    int* packed = (int*)(ws + off);  off += (size_t)E * 4;           // 6.4 MB
    unsigned short* wexp = (unsigned short*)(ws + off);
    off += (size_t)E * sizeof(unsigned short);                        // 3.2 MB
    int* nstart = (int*)(ws + off);  off += ((size_t)NB * BUCKET_SIZE + 8) * 4;  // 0.4 MB
    int* bstart = (int*)(ws + off);  off += ((size_t)NB + 1) * 4;
    int* bsum   = (int*)(ws + off);  off += (size_t)NB * 4;
    int* cursor = (int*)(ws + off);  off += (size_t)NB * 4;
    const size_t csr_total = off;    // ~17.2 MB
    float* denom = (float*)(ws + base);

    const bool use_csr = (ws_size >= csr_total);

    if (use_csr) {
        hipMemsetAsync(bsum, 0, (size_t)NB * 4, stream);
        const int waves = (N_NODES + 15) / 16;                 // 6250
        const int blocks_z = (waves + 3) / 4;                  // 1563
        const int grid_k1 = (blocks_z > nblk) ? blocks_z : nblk;
        k1_fused<<<grid_k1, 256, 0, stream>>>(h, fc_w, attn_w, dst, zbf, s_l, s_r,
                                              bsum, E, nblk);
        k_scan_top<<<1, 1024, 0, stream>>>(bsum, bstart, cursor);
        k_scatter3<<<nblk, 256, 0, stream>>>(src, dst, cursor, packed, E);
        k_place_w<<<NB, 256, 0, stream>>>(bstart, packed, nstart, s_l, s_r, wexp);
        const int blocks_g = (N_NODES * 64 + 255) / 256;
        k_gather8w<<<blocks_g, 256, 0, stream>>>(nstart, packed, wexp, zbf, out);
    } else {
        const int blocks_k1 = (N_NODES + 255) / 256;
        k1_z_scores<<<blocks_k1, 256, 0, stream>>>(h, fc_w, attn_w, zbf, s_l, s_r, denom, out);
        const long long tot = (long long)E * 8;
        const int blocks_k3 = (int)((tot + 255) / 256);
        k3_edges<<<blocks_k3, 256, 0, stream>>>(src, dst, s_l, s_r, zbf, denom, out, E);
        const int blocks_k4 = (N_NODES * OUT_DIM + 255) / 256;
        k4_finalize<<<blocks_k4, 256, 0, stream>>>(denom, out);
    }
}

// Round 11
// 218.418 us; speedup vs baseline: 1.3545x; 1.3545x over previous
//
#include <hip/hip_runtime.h>
#include <hip/hip_bf16.h>

#define N_NODES 100000
#define IN_DIM 128
#define OUT_DIM 32
#define NEG_SLOPE 0.01f
#define E_DEFAULT 1600000
#define BUCKET_SHIFT 7
#define BUCKET_SIZE 128
#define NB ((N_NODES + BUCKET_SIZE - 1) / BUCKET_SIZE)   // 782
#define ECHUNK_S 8192    // scatter/hist chunk: run length ~10.5 (measured best)
#define PCAP 8192
#define WPAD 136   // bf16 LDS row stride for fc_w (16B-aligned, bank-balanced)

typedef __attribute__((ext_vector_type(8))) short bf16x8;
typedef __attribute__((ext_vector_type(4))) float f32x4;

__device__ __forceinline__ float bfu2f(unsigned int u16) {
    union { unsigned int i; float f; } v;
    v.i = u16 << 16;
    return v.f;
}
__device__ __forceinline__ unsigned short f2bfu(float f) {
    union { unsigned int i; float f; } v;
    v.f = f;
    unsigned int r = v.i + 0x7fffu + ((v.i >> 16) & 1u);  // RNE
    return (unsigned short)(r >> 16);
}

// K1 (MFMA): z = h @ fc_w^T. One wave = 16 nodes x 32 dims, K=128.
__global__ __launch_bounds__(256) void k1_mfma(
    const float* __restrict__ h,
    const float* __restrict__ fc_w,
    const float* __restrict__ attn_w,
    unsigned short* __restrict__ zbf,
    float* __restrict__ s_l,
    float* __restrict__ s_r) {
    __shared__ unsigned short wlds[OUT_DIM * WPAD];  // 8.5 KB bf16
    __shared__ float al[OUT_DIM], ar[OUT_DIM];

    const int t = threadIdx.x;
    for (int i = t; i < OUT_DIM * IN_DIM / 4; i += 256) {
        const float4 v = ((const float4*)fc_w)[i];
        const int idx = i * 4;
        const int row = idx >> 7, col = idx & 127;
        unsigned short* p = &wlds[row * WPAD + col];
        p[0] = f2bfu(v.x); p[1] = f2bfu(v.y); p[2] = f2bfu(v.z); p[3] = f2bfu(v.w);
    }
    if (t < 2 * OUT_DIM) {
        if (t < OUT_DIM) al[t] = attn_w[t];
        else ar[t - OUT_DIM] = attn_w[t];
    }
    __syncthreads();

    const int wid = blockIdx.x * 4 + (t >> 6);
    int base = wid * 16;
    if (base > N_NODES - 16) base = N_NODES - 16;   // clamp: duplicates benign
    const int lane = t & 63;
    const int row16 = lane & 15;
    const int quad = lane >> 4;

    f32x4 acc0 = {0.f, 0.f, 0.f, 0.f};
    f32x4 acc1 = {0.f, 0.f, 0.f, 0.f};
    const float* hrow = h + (size_t)(base + row16) * IN_DIM + quad * 8;
    const unsigned short* b0 = &wlds[row16 * WPAD + quad * 8];
    const unsigned short* b1 = &wlds[(row16 + 16) * WPAD + quad * 8];

#pragma unroll
    for (int s = 0; s < 4; ++s) {
        const float4 a0 = *(const float4*)(hrow + s * 32);
        const float4 a1 = *(const float4*)(hrow + s * 32 + 4);
        bf16x8 af;
        af[0] = (short)f2bfu(a0.x); af[1] = (short)f2bfu(a0.y);
        af[2] = (short)f2bfu(a0.z); af[3] = (short)f2bfu(a0.w);
        af[4] = (short)f2bfu(a1.x); af[5] = (short)f2bfu(a1.y);
        af[6] = (short)f2bfu(a1.z); af[7] = (short)f2bfu(a1.w);
        const bf16x8 bf0 = *(const bf16x8*)(b0 + s * 32);
        const bf16x8 bf1 = *(const bf16x8*)(b1 + s * 32);
        acc0 = __builtin_amdgcn_mfma_f32_16x16x32_bf16(af, bf0, acc0, 0, 0, 0);
        acc1 = __builtin_amdgcn_mfma_f32_16x16x32_bf16(af, bf1, acc1, 0, 0, 0);
    }

    const float al_lo = al[row16], al_hi = al[row16 + 16];
    const float ar_lo = ar[row16], ar_hi = ar[row16 + 16];
#pragma unroll
    for (int r = 0; r < 4; ++r) {
        const int node = base + quad * 4 + r;
        float p = acc0[r] * al_lo + acc1[r] * al_hi;
        float q = acc0[r] * ar_lo + acc1[r] * ar_hi;
        p += __shfl_xor(p, 1, 64); p += __shfl_xor(p, 2, 64);
        p += __shfl_xor(p, 4, 64); p += __shfl_xor(p, 8, 64);
        q += __shfl_xor(q, 1, 64); q += __shfl_xor(q, 2, 64);
        q += __shfl_xor(q, 4, 64); q += __shfl_xor(q, 8, 64);
        if (row16 == 0) { s_l[node] = p; s_r[node] = q; }
        zbf[(size_t)node * OUT_DIM + row16] = f2bfu(acc0[r]);
        zbf[(size_t)node * OUT_DIM + 16 + row16] = f2bfu(acc1[r]);
    }
}

// LDS-hist per 8192-edge chunk -> one global atomic per nonzero bin.
__global__ __launch_bounds__(256) void k_hist8k(
    const int* __restrict__ dst, int* __restrict__ bsum, int E) {
    __shared__ int bins[NB];
    const int t = threadIdx.x;
    for (int i = t; i < NB; i += 256) bins[i] = 0;
    __syncthreads();
    const int e0 = blockIdx.x * ECHUNK_S;
#pragma unroll
    for (int k = 0; k < ECHUNK_S; k += 256) {
        const int e = e0 + k + t;
        if (e < E) atomicAdd(&bins[dst[e] >> BUCKET_SHIFT], 1);
    }
    __syncthreads();
    for (int i = t; i < NB; i += 256) {
        const int c = bins[i];
        if (c) atomicAdd(&bsum[i], c);
    }
}

// 1 block: exclusive scan over bucket totals -> bstart; init global cursors.
__global__ __launch_bounds__(1024) void k_scan_top(
    const int* __restrict__ bsum, int* __restrict__ bstart,
    int* __restrict__ cursor) {
    __shared__ int sc[1024];
    const int t = threadIdx.x;
    const int v = (t < NB) ? bsum[t] : 0;
    sc[t] = v;
    __syncthreads();
    for (int off = 1; off < 1024; off <<= 1) {
        const int u = (t >= off) ? sc[t - off] : 0;
        __syncthreads();
        sc[t] += u;
        __syncthreads();
    }
    if (t < NB) {
        const int st = sc[t] - v;
        bstart[t] = st;
        cursor[t] = st;
    }
    if (t == 1023) bstart[NB] = sc[1023];
}

// Two-pass scatter @8192: LDS hist -> one global range-reservation atomic per
// nonzero bin -> LDS-cursor placement of packed {ldst:7|src:17}.
// Run length ~10.5 edges/bin/block -> low write amplification (measured r8).
__global__ __launch_bounds__(256) void k_scatter3(
    const int* __restrict__ src, const int* __restrict__ dst,
    int* __restrict__ cursor, int* __restrict__ packed, int E) {
    __shared__ int bins[NB];
    __shared__ int basep[NB];
    const int t = threadIdx.x;
    for (int i = t; i < NB; i += 256) bins[i] = 0;
    __syncthreads();
    const int e0 = blockIdx.x * ECHUNK_S;
#pragma unroll
    for (int k = 0; k < ECHUNK_S; k += 256) {
        const int e = e0 + k + t;
        if (e < E) atomicAdd(&bins[dst[e] >> BUCKET_SHIFT], 1);
    }
    __syncthreads();
    for (int i = t; i < NB; i += 256) {
        const int c = bins[i];
        basep[i] = c ? atomicAdd(&cursor[i], c) : 0;
        bins[i] = 0;   // reuse as local cursor
    }
    __syncthreads();
#pragma unroll
    for (int k = 0; k < ECHUNK_S; k += 256) {
        const int e = e0 + k + t;
        if (e < E) {
            const int d = dst[e];
            const int bin = d >> BUCKET_SHIFT;
            const int pos = basep[bin] + atomicAdd(&bins[bin], 1);
            packed[pos] = ((d & (BUCKET_SIZE - 1)) << 17) | src[e];
        }
    }
}

// One block per bucket: LDS stage, per-node count + scan -> nstart, permute
// to node-sorted src, and compute per-edge weight w = exp(lrelu(.)) once (bf16).
__global__ __launch_bounds__(256) void k_place_w(
    const int* __restrict__ bstart,
    int* __restrict__ packed,
    int* __restrict__ nstart,
    const float* __restrict__ s_l,
    const float* __restrict__ s_r,
    unsigned short* __restrict__ wexp) {
    __shared__ int pk[PCAP];
    __shared__ int cnt128[BUCKET_SIZE];
    __shared__ int pref[BUCKET_SIZE];
    __shared__ int cur[BUCKET_SIZE];
    __shared__ float srt[BUCKET_SIZE];

    const int bin = blockIdx.x;
    const int base = bin * BUCKET_SIZE;
    const int st = bstart[bin];
    int cnt = bstart[bin + 1] - st;
    if (cnt > PCAP) cnt = PCAP;
    const int t = threadIdx.x;

    if (t < BUCKET_SIZE) {
        cnt128[t] = 0;
        const int n = base + t;
        srt[t] = (n < N_NODES) ? s_r[n] : 0.f;
    }
    __syncthreads();
    for (int i = t; i < cnt; i += 256) {
        const int p = packed[st + i];
        pk[i] = p;
        atomicAdd(&cnt128[p >> 17], 1);
    }
    __syncthreads();
    if (t < BUCKET_SIZE) pref[t] = cnt128[t];
    __syncthreads();
    for (int off = 1; off < BUCKET_SIZE; off <<= 1) {
        int u = 0;
        if (t < BUCKET_SIZE && t >= off) u = pref[t - off];
        __syncthreads();
        if (t < BUCKET_SIZE) pref[t] += u;
        __syncthreads();
    }
    if (t < BUCKET_SIZE) {
        const int excl = pref[t] - cnt128[t];
        nstart[base + t] = st + excl;
        cur[t] = excl;
    }
    __syncthreads();
    for (int i = t; i < cnt; i += 256) {
        const int p = pk[i];
        const int ldst = p >> 17;
        const int sn = p & 0x1FFFF;
        const int pos = st + atomicAdd(&cur[ldst], 1);
        float x = s_l[sn] + srt[ldst];
        x = (x > 0.f) ? x : NEG_SLOPE * x;
        packed[pos] = sn;
        wexp[pos] = f2bfu(__expf(x));
    }
}

// One wave per node: 8 edge streams x 8 dim-groups. No exp, no s_l — weight
// preloaded bf16. Chain: nstart -> (packed,wexp) -> zbf.
__global__ __launch_bounds__(256) void k_gather8w(
    const int* __restrict__ nstart,
    const int* __restrict__ esrc,
    const unsigned short* __restrict__ wexp,
    const unsigned short* __restrict__ zbf,
    float* __restrict__ out) {
    const int gtid = blockIdx.x * 256 + threadIdx.x;
    const int n = gtid >> 6;
    if (n >= N_NODES) return;
    const int lane = gtid & 63;
    const int eslot = lane >> 3;
    const int dimg = lane & 7;

    const int st = nstart[n];
    const int cnt = nstart[n + 1] - st;

    float a0 = 0.f, a1 = 0.f, a2 = 0.f, a3 = 0.f, dn = 0.f;
    for (int i = eslot; i < cnt; i += 8) {
        const int es = esrc[st + i];
        const float w = bfu2f(wexp[st + i]);
        const uint2 zv = *(const uint2*)&zbf[(size_t)es * OUT_DIM + dimg * 4];
        a0 += w * bfu2f(zv.x & 0xffffu);
        a1 += w * bfu2f(zv.x >> 16);
        a2 += w * bfu2f(zv.y & 0xffffu);
        a3 += w * bfu2f(zv.y >> 16);
        dn += w;
    }
#pragma unroll
    for (int m = 8; m < 64; m <<= 1) {
        a0 += __shfl_xor(a0, m, 64);
        a1 += __shfl_xor(a1, m, 64);
        a2 += __shfl_xor(a2, m, 64);
        a3 += __shfl_xor(a3, m, 64);
        dn += __shfl_xor(dn, m, 64);
    }
    if (eslot == 0) {
        const float inv = (dn > 0.f) ? 1.f / dn : 0.f;
        *(float4*)&out[(size_t)n * OUT_DIM + dimg * 4] =
            make_float4(a0 * inv, a1 * inv, a2 * inv, a3 * inv);
    }
}

// ---------------- atomic fallback path (known-passing) ----------

__global__ __launch_bounds__(256) void k1_z_scores(
    const float* __restrict__ h,
    const float* __restrict__ fc_w,
    const float* __restrict__ attn_w,
    unsigned short* __restrict__ zbf,
    float* __restrict__ s_l,
    float* __restrict__ s_r,
    float* __restrict__ denom,
    float* __restrict__ out) {
    __shared__ float wlds[OUT_DIM * IN_DIM];
    __shared__ float al[OUT_DIM], ar[OUT_DIM];

    const int tid = threadIdx.x;
    for (int i = tid; i < OUT_DIM * IN_DIM; i += 256) wlds[i] = fc_w[i];
    if (tid < OUT_DIM) {
        al[tid] = attn_w[tid];
        ar[tid] = attn_w[OUT_DIM + tid];
    }
    __syncthreads();

    const int node = blockIdx.x * 256 + tid;
    if (node >= N_NODES) return;

    float acc[OUT_DIM];
#pragma unroll
    for (int j = 0; j < OUT_DIM; ++j) acc[j] = 0.f;
    const float4* hp = (const float4*)(h + (size_t)node * IN_DIM);
#pragma unroll 4
    for (int kg = 0; kg < IN_DIM / 4; ++kg) {
        const float4 hv = hp[kg];
#pragma unroll
        for (int j = 0; j < OUT_DIM; ++j) {
            const float4 w = *(const float4*)&wlds[j * IN_DIM + kg * 4];
            acc[j] += hv.x * w.x + hv.y * w.y + hv.z * w.z + hv.w * w.w;
        }
    }
    float sl = 0.f, sr = 0.f;
#pragma unroll
    for (int j = 0; j < OUT_DIM; ++j) { sl += acc[j] * al[j]; sr += acc[j] * ar[j]; }
    s_l[node] = sl; s_r[node] = sr; denom[node] = 0.f;
    uint4* zp = (uint4*)(zbf + (size_t)node * OUT_DIM);
#pragma unroll
    for (int q = 0; q < 4; ++q) {
        uint4 pk;
        pk.x = (unsigned int)f2bfu(acc[8 * q + 0]) | ((unsigned int)f2bfu(acc[8 * q + 1]) << 16);
        pk.y = (unsigned int)f2bfu(acc[8 * q + 2]) | ((unsigned int)f2bfu(acc[8 * q + 3]) << 16);
        pk.z = (unsigned int)f2bfu(acc[8 * q + 4]) | ((unsigned int)f2bfu(acc[8 * q + 5]) << 16);
        pk.w = (unsigned int)f2bfu(acc[8 * q + 6]) | ((unsigned int)f2bfu(acc[8 * q + 7]) << 16);
        zp[q] = pk;
    }
    float4* op = (float4*)(out + (size_t)node * OUT_DIM);
    const float4 zero4 = make_float4(0.f, 0.f, 0.f, 0.f);
#pragma unroll
    for (int q = 0; q < 8; ++q) op[q] = zero4;
}

__global__ __launch_bounds__(256) void k3_edges(
    const int* __restrict__ src, const int* __restrict__ dst,
    const float* __restrict__ s_l, const float* __restrict__ s_r,
    const unsigned short* __restrict__ zbf,
    float* __restrict__ denom, float* __restrict__ out, int E) {
    const long long gid = (long long)blockIdx.x * 256 + threadIdx.x;
    const int e = (int)(gid >> 3);
    const int q = (int)(gid & 7);
    if (e >= E) return;
    const int s = src[e];
    const int d = dst[e];
    float x = s_l[s] + s_r[d];
    x = (x > 0.f) ? x : NEG_SLOPE * x;
    const float w = __expf(x);
    const uint2 zv = *(const uint2*)&zbf[(size_t)s * OUT_DIM + q * 4];
    float* op = &out[(size_t)d * OUT_DIM + q * 4];
    unsafeAtomicAdd(op + 0, w * bfu2f(zv.x & 0xffffu));
    unsafeAtomicAdd(op + 1, w * bfu2f(zv.x >> 16));
    unsafeAtomicAdd(op + 2, w * bfu2f(zv.y & 0xffffu));
    unsafeAtomicAdd(op + 3, w * bfu2f(zv.y >> 16));
    if (q == 0) unsafeAtomicAdd(&denom[d], w);
}

__global__ __launch_bounds__(256) void k4_finalize(
    const float* __restrict__ denom, float* __restrict__ out) {
    const int i = blockIdx.x * 256 + threadIdx.x;
    if (i >= N_NODES * OUT_DIM) return;
    const float dnm = denom[i >> 5];
    out[i] = (dnm > 0.f) ? out[i] / dnm : 0.f;
}

extern "C" void kernel_launch(void* const* d_in, const int* in_sizes, int n_in,
                              void* d_out, int out_size, void* d_ws, size_t ws_size,
                              hipStream_t stream) {
    const float* h      = (const float*)d_in[0];
    const int*   src    = (const int*)d_in[1];
    const int*   dst    = (const int*)d_in[2];
    const float* fc_w   = (const float*)d_in[3];
    const float* attn_w = (const float*)d_in[4];
    float* out = (float*)d_out;
    const int E = (in_sizes[1] > 0) ? in_sizes[1] : E_DEFAULT;
    const int nblk_s = (E + ECHUNK_S - 1) / ECHUNK_S;     // 196

    char* ws = (char*)d_ws;
    size_t off = 0;
    unsigned short* zbf = (unsigned short*)(ws + off);
    off += (size_t)N_NODES * OUT_DIM * sizeof(unsigned short);       // 6.4 MB
    float* s_l = (float*)(ws + off); off += (size_t)N_NODES * 4;     // 0.4 MB
    float* s_r = (float*)(ws + off); off += (size_t)N_NODES * 4;     // 0.4 MB

    const size_t base = off;
    int* packed = (int*)(ws + off);  off += (size_t)E * 4;           // 6.4 MB
    unsigned short* wexp = (unsigned short*)(ws + off);
    off += (size_t)E * sizeof(unsigned short);                        // 3.2 MB
    int* nstart = (int*)(ws + off);  off += ((size_t)NB * BUCKET_SIZE + 8) * 4;  // 0.4 MB
    int* bstart = (int*)(ws + off);  off += ((size_t)NB + 1) * 4;
    int* bsum   = (int*)(ws + off);  off += (size_t)NB * 4;
    int* cursor = (int*)(ws + off);  off += (size_t)NB * 4;
    const size_t csr_total = off;    // ~17.2 MB
    float* denom = (float*)(ws + base);

    const bool use_csr = (ws_size >= csr_total);

    if (use_csr) {
        hipMemsetAsync(bsum, 0, (size_t)NB * 4, stream);
        const int waves = (N_NODES + 15) / 16;                 // 6250
        const int blocks_z = (waves + 3) / 4;                  // 1563
        k1_mfma<<<blocks_z, 256, 0, stream>>>(h, fc_w, attn_w, zbf, s_l, s_r);
        k_hist8k<<<nblk_s, 256, 0, stream>>>(dst, bsum, E);
        k_scan_top<<<1, 1024, 0, stream>>>(bsum, bstart, cursor);
        k_scatter3<<<nblk_s, 256, 0, stream>>>(src, dst, cursor, packed, E);
        k_place_w<<<NB, 256, 0, stream>>>(bstart, packed, nstart, s_l, s_r, wexp);
        const int blocks_g = (N_NODES * 64 + 255) / 256;
        k_gather8w<<<blocks_g, 256, 0, stream>>>(nstart, packed, wexp, zbf, out);
    } else {
        const int blocks_k1 = (N_NODES + 255) / 256;
        k1_z_scores<<<blocks_k1, 256, 0, stream>>>(h, fc_w, attn_w, zbf, s_l, s_r, denom, out);
        const long long tot = (long long)E * 8;
        const int blocks_k3 = (int)((tot + 255) / 256);
        k3_edges<<<blocks_k3, 256, 0, stream>>>(src, dst, s_l, s_r, zbf, denom, out, E);
        const int blocks_k4 = (N_NODES * OUT_DIM + 255) / 256;
        k4_finalize<<<blocks_k4, 256, 0, stream>>>(denom, out);
    }
}

// Round 12
// 171.537 us; speedup vs baseline: 1.7247x; 1.2733x over previous
//
#include <hip/hip_runtime.h>
#include <hip/hip_bf16.h>

#define N_NODES 100000
#define IN_DIM 128
#define OUT_DIM 32
#define NEG_SLOPE 0.01f
#define E_DEFAULT 1600000
#define BUCKET_SHIFT 7
#define BUCKET_SIZE 128
#define NB ((N_NODES + BUCKET_SIZE - 1) / BUCKET_SIZE)   // 782
#define ECHUNK_S 8192    // scatter chunk: run length ~10.5/bin (measured best)
#define CAP 2432         // fixed bucket slot: mean 2046 + 8.5 sigma (sd ~45)
#define WPAD 136         // bf16 LDS row stride for fc_w

typedef __attribute__((ext_vector_type(8))) short bf16x8;
typedef __attribute__((ext_vector_type(4))) float f32x4;

__device__ __forceinline__ float bfu2f(unsigned int u16) {
    union { unsigned int i; float f; } v;
    v.i = u16 << 16;
    return v.f;
}
__device__ __forceinline__ unsigned short f2bfu(float f) {
    union { unsigned int i; float f; } v;
    v.f = f;
    unsigned int r = v.i + 0x7fffu + ((v.i >> 16) & 1u);  // RNE
    return (unsigned short)(r >> 16);
}

// Init fixed-slot cursors: cursor[bin] = bin*CAP.
__global__ __launch_bounds__(256) void k_init_cursor(int* __restrict__ cursor) {
    const int i = blockIdx.x * 256 + threadIdx.x;
    if (i < NB) cursor[i] = i * CAP;
}

// K1 (MFMA): z = h @ fc_w^T. One wave = 16 nodes x 32 dims, K=128 (r7-proven).
__global__ __launch_bounds__(256) void k1_mfma(
    const float* __restrict__ h,
    const float* __restrict__ fc_w,
    const float* __restrict__ attn_w,
    unsigned short* __restrict__ zbf,
    float* __restrict__ s_l,
    float* __restrict__ s_r) {
    __shared__ unsigned short wlds[OUT_DIM * WPAD];  // 8.5 KB bf16
    __shared__ float al[OUT_DIM], ar[OUT_DIM];

    const int t = threadIdx.x;
    for (int i = t; i < OUT_DIM * IN_DIM / 4; i += 256) {
        const float4 v = ((const float4*)fc_w)[i];
        const int idx = i * 4;
        const int row = idx >> 7, col = idx & 127;
        unsigned short* p = &wlds[row * WPAD + col];
        p[0] = f2bfu(v.x); p[1] = f2bfu(v.y); p[2] = f2bfu(v.z); p[3] = f2bfu(v.w);
    }
    if (t < 2 * OUT_DIM) {
        if (t < OUT_DIM) al[t] = attn_w[t];
        else ar[t - OUT_DIM] = attn_w[t];
    }
    __syncthreads();

    const int wid = blockIdx.x * 4 + (t >> 6);
    int base = wid * 16;
    if (base > N_NODES - 16) base = N_NODES - 16;   // clamp: duplicates benign
    const int lane = t & 63;
    const int row16 = lane & 15;
    const int quad = lane >> 4;

    f32x4 acc0 = {0.f, 0.f, 0.f, 0.f};
    f32x4 acc1 = {0.f, 0.f, 0.f, 0.f};
    const float* hrow = h + (size_t)(base + row16) * IN_DIM + quad * 8;
    const unsigned short* b0 = &wlds[row16 * WPAD + quad * 8];
    const unsigned short* b1 = &wlds[(row16 + 16) * WPAD + quad * 8];

#pragma unroll
    for (int s = 0; s < 4; ++s) {
        const float4 a0 = *(const float4*)(hrow + s * 32);
        const float4 a1 = *(const float4*)(hrow + s * 32 + 4);
        bf16x8 af;
        af[0] = (short)f2bfu(a0.x); af[1] = (short)f2bfu(a0.y);
        af[2] = (short)f2bfu(a0.z); af[3] = (short)f2bfu(a0.w);
        af[4] = (short)f2bfu(a1.x); af[5] = (short)f2bfu(a1.y);
        af[6] = (short)f2bfu(a1.z); af[7] = (short)f2bfu(a1.w);
        const bf16x8 bf0 = *(const bf16x8*)(b0 + s * 32);
        const bf16x8 bf1 = *(const bf16x8*)(b1 + s * 32);
        acc0 = __builtin_amdgcn_mfma_f32_16x16x32_bf16(af, bf0, acc0, 0, 0, 0);
        acc1 = __builtin_amdgcn_mfma_f32_16x16x32_bf16(af, bf1, acc1, 0, 0, 0);
    }

    const float al_lo = al[row16], al_hi = al[row16 + 16];
    const float ar_lo = ar[row16], ar_hi = ar[row16 + 16];
#pragma unroll
    for (int r = 0; r < 4; ++r) {
        const int node = base + quad * 4 + r;
        float p = acc0[r] * al_lo + acc1[r] * al_hi;
        float q = acc0[r] * ar_lo + acc1[r] * ar_hi;
        p += __shfl_xor(p, 1, 64); p += __shfl_xor(p, 2, 64);
        p += __shfl_xor(p, 4, 64); p += __shfl_xor(p, 8, 64);
        q += __shfl_xor(q, 1, 64); q += __shfl_xor(q, 2, 64);
        q += __shfl_xor(q, 4, 64); q += __shfl_xor(q, 8, 64);
        if (row16 == 0) { s_l[node] = p; s_r[node] = q; }
        zbf[(size_t)node * OUT_DIM + row16] = f2bfu(acc0[r]);
        zbf[(size_t)node * OUT_DIM + 16 + row16] = f2bfu(acc1[r]);
    }
}

// Two-pass scatter @8192, 512 threads (8 waves): LDS hist -> range reservation
// from fixed-slot cursors -> LDS-cursor placement of packed {ldst:7|src:17}.
__global__ __launch_bounds__(512) void k_scatter3b(
    const int* __restrict__ src, const int* __restrict__ dst,
    int* __restrict__ cursor, int* __restrict__ packed, int E) {
    __shared__ int bins[NB];
    __shared__ int basep[NB];
    const int t = threadIdx.x;
    for (int i = t; i < NB; i += 512) bins[i] = 0;
    __syncthreads();
    const int e0 = blockIdx.x * ECHUNK_S;
#pragma unroll 4
    for (int k = 0; k < ECHUNK_S; k += 512) {
        const int e = e0 + k + t;
        if (e < E) atomicAdd(&bins[dst[e] >> BUCKET_SHIFT], 1);
    }
    __syncthreads();
    for (int i = t; i < NB; i += 512) {
        const int c = bins[i];
        basep[i] = c ? atomicAdd(&cursor[i], c) : 0;
        bins[i] = 0;   // reuse as local cursor
    }
    __syncthreads();
#pragma unroll 4
    for (int k = 0; k < ECHUNK_S; k += 512) {
        const int e = e0 + k + t;
        if (e < E) {
            const int d = dst[e];
            const int bin = d >> BUCKET_SHIFT;
            const int pos = basep[bin] + atomicAdd(&bins[bin], 1);
            if (pos < (bin + 1) * CAP)   // overflow guard (never fires: 8.5 sigma)
                packed[pos] = ((d & (BUCKET_SIZE - 1)) << 17) | src[e];
        }
    }
}

// One block per bucket (512 thr, 8 waves): stage packed run, LDS node-sort,
// per-edge w=exp(lrelu(s_l[src]+s_r[dst])) into LDS (fp32), then gather:
// each wave = 16 nodes, 8 edge-streams x 8 dim-groups, fused /denom + store.
__global__ __launch_bounds__(512) void k_bucket_gather(
    const int* __restrict__ cursor,
    const int* __restrict__ packed,
    const float* __restrict__ s_l,
    const float* __restrict__ s_r,
    const unsigned short* __restrict__ zbf,
    float* __restrict__ out) {
    __shared__ int pk[CAP];
    __shared__ int srcs[CAP];
    __shared__ float wl[CAP];
    __shared__ int cnt128[BUCKET_SIZE];
    __shared__ int pref[BUCKET_SIZE];
    __shared__ int cur[BUCKET_SIZE];
    __shared__ float srt[BUCKET_SIZE];

    const int bin = blockIdx.x;
    const int nbase = bin * BUCKET_SIZE;
    const int pbase = bin * CAP;
    const int t = threadIdx.x;
    int cnt = cursor[bin] - pbase;
    if (cnt > CAP) cnt = CAP;
    if (cnt < 0) cnt = 0;

    if (t < BUCKET_SIZE) {
        cnt128[t] = 0;
        const int n = nbase + t;
        srt[t] = (n < N_NODES) ? s_r[n] : 0.f;
    }
    __syncthreads();
    for (int i = t; i < cnt; i += 512) {
        const int p = packed[pbase + i];
        pk[i] = p;
        atomicAdd(&cnt128[p >> 17], 1);
    }
    __syncthreads();
    if (t < BUCKET_SIZE) pref[t] = cnt128[t];
    __syncthreads();
    for (int off = 1; off < BUCKET_SIZE; off <<= 1) {
        int u = 0;
        if (t < BUCKET_SIZE && t >= off) u = pref[t - off];
        __syncthreads();
        if (t < BUCKET_SIZE) pref[t] += u;
        __syncthreads();
    }
    if (t < BUCKET_SIZE) cur[t] = pref[t] - cnt128[t];   // exclusive start
    __syncthreads();
    for (int i = t; i < cnt; i += 512) {
        const int p = pk[i];
        const int ldst = p >> 17;
        const int sn = p & 0x1FFFF;
        const int pos = atomicAdd(&cur[ldst], 1);
        float x = s_l[sn] + srt[ldst];
        x = (x > 0.f) ? x : NEG_SLOPE * x;
        srcs[pos] = sn;
        wl[pos] = __expf(x);
    }
    __syncthreads();

    const int wv = t >> 6;          // 8 waves
    const int lane = t & 63;
    const int eslot = lane >> 3;    // 8 edge streams
    const int dimg = lane & 7;      // 8 dim groups x 4 dims
#pragma unroll 2
    for (int j = 0; j < 16; ++j) {
        const int ln = wv * 16 + j;
        const int st = pref[ln] - cnt128[ln];
        const int ce = pref[ln];
        float a0 = 0.f, a1 = 0.f, a2 = 0.f, a3 = 0.f, dn = 0.f;
        for (int i = st + eslot; i < ce; i += 8) {
            const int es = srcs[i];
            const float w = wl[i];
            const uint2 zv = *(const uint2*)&zbf[(size_t)es * OUT_DIM + dimg * 4];
            a0 += w * bfu2f(zv.x & 0xffffu);
            a1 += w * bfu2f(zv.x >> 16);
            a2 += w * bfu2f(zv.y & 0xffffu);
            a3 += w * bfu2f(zv.y >> 16);
            dn += w;
        }
#pragma unroll
        for (int m = 8; m < 64; m <<= 1) {
            a0 += __shfl_xor(a0, m, 64);
            a1 += __shfl_xor(a1, m, 64);
            a2 += __shfl_xor(a2, m, 64);
            a3 += __shfl_xor(a3, m, 64);
            dn += __shfl_xor(dn, m, 64);
        }
        const int n = nbase + ln;
        if (eslot == 0 && n < N_NODES) {
            const float inv = (dn > 0.f) ? 1.f / dn : 0.f;
            *(float4*)&out[(size_t)n * OUT_DIM + dimg * 4] =
                make_float4(a0 * inv, a1 * inv, a2 * inv, a3 * inv);
        }
    }
}

// ---------------- atomic fallback path (known-passing) ----------

__global__ __launch_bounds__(256) void k1_z_scores(
    const float* __restrict__ h,
    const float* __restrict__ fc_w,
    const float* __restrict__ attn_w,
    unsigned short* __restrict__ zbf,
    float* __restrict__ s_l,
    float* __restrict__ s_r,
    float* __restrict__ denom,
    float* __restrict__ out) {
    __shared__ float wlds[OUT_DIM * IN_DIM];
    __shared__ float al[OUT_DIM], ar[OUT_DIM];

    const int tid = threadIdx.x;
    for (int i = tid; i < OUT_DIM * IN_DIM; i += 256) wlds[i] = fc_w[i];
    if (tid < OUT_DIM) {
        al[tid] = attn_w[tid];
        ar[tid] = attn_w[OUT_DIM + tid];
    }
    __syncthreads();

    const int node = blockIdx.x * 256 + tid;
    if (node >= N_NODES) return;

    float acc[OUT_DIM];
#pragma unroll
    for (int j = 0; j < OUT_DIM; ++j) acc[j] = 0.f;
    const float4* hp = (const float4*)(h + (size_t)node * IN_DIM);
#pragma unroll 4
    for (int kg = 0; kg < IN_DIM / 4; ++kg) {
        const float4 hv = hp[kg];
#pragma unroll
        for (int j = 0; j < OUT_DIM; ++j) {
            const float4 w = *(const float4*)&wlds[j * IN_DIM + kg * 4];
            acc[j] += hv.x * w.x + hv.y * w.y + hv.z * w.z + hv.w * w.w;
        }
    }
    float sl = 0.f, sr = 0.f;
#pragma unroll
    for (int j = 0; j < OUT_DIM; ++j) { sl += acc[j] * al[j]; sr += acc[j] * ar[j]; }
    s_l[node] = sl; s_r[node] = sr; denom[node] = 0.f;
    uint4* zp = (uint4*)(zbf + (size_t)node * OUT_DIM);
#pragma unroll
    for (int q = 0; q < 4; ++q) {
        uint4 pk;
        pk.x = (unsigned int)f2bfu(acc[8 * q + 0]) | ((unsigned int)f2bfu(acc[8 * q + 1]) << 16);
        pk.y = (unsigned int)f2bfu(acc[8 * q + 2]) | ((unsigned int)f2bfu(acc[8 * q + 3]) << 16);
        pk.z = (unsigned int)f2bfu(acc[8 * q + 4]) | ((unsigned int)f2bfu(acc[8 * q + 5]) << 16);
        pk.w = (unsigned int)f2bfu(acc[8 * q + 6]) | ((unsigned int)f2bfu(acc[8 * q + 7]) << 16);
        zp[q] = pk;
    }
    float4* op = (float4*)(out + (size_t)node * OUT_DIM);
    const float4 zero4 = make_float4(0.f, 0.f, 0.f, 0.f);
#pragma unroll
    for (int q = 0; q < 8; ++q) op[q] = zero4;
}

__global__ __launch_bounds__(256) void k3_edges(
    const int* __restrict__ src, const int* __restrict__ dst,
    const float* __restrict__ s_l, const float* __restrict__ s_r,
    const unsigned short* __restrict__ zbf,
    float* __restrict__ denom, float* __restrict__ out, int E) {
    const long long gid = (long long)blockIdx.x * 256 + threadIdx.x;
    const int e = (int)(gid >> 3);
    const int q = (int)(gid & 7);
    if (e >= E) return;
    const int s = src[e];
    const int d = dst[e];
    float x = s_l[s] + s_r[d];
    x = (x > 0.f) ? x : NEG_SLOPE * x;
    const float w = __expf(x);
    const uint2 zv = *(const uint2*)&zbf[(size_t)s * OUT_DIM + q * 4];
    float* op = &out[(size_t)d * OUT_DIM + q * 4];
    unsafeAtomicAdd(op + 0, w * bfu2f(zv.x & 0xffffu));
    unsafeAtomicAdd(op + 1, w * bfu2f(zv.x >> 16));
    unsafeAtomicAdd(op + 2, w * bfu2f(zv.y & 0xffffu));
    unsafeAtomicAdd(op + 3, w * bfu2f(zv.y >> 16));
    if (q == 0) unsafeAtomicAdd(&denom[d], w);
}

__global__ __launch_bounds__(256) void k4_finalize(
    const float* __restrict__ denom, float* __restrict__ out) {
    const int i = blockIdx.x * 256 + threadIdx.x;
    if (i >= N_NODES * OUT_DIM) return;
    const float dnm = denom[i >> 5];
    out[i] = (dnm > 0.f) ? out[i] / dnm : 0.f;
}

extern "C" void kernel_launch(void* const* d_in, const int* in_sizes, int n_in,
                              void* d_out, int out_size, void* d_ws, size_t ws_size,
                              hipStream_t stream) {
    const float* h      = (const float*)d_in[0];
    const int*   src    = (const int*)d_in[1];
    const int*   dst    = (const int*)d_in[2];
    const float* fc_w   = (const float*)d_in[3];
    const float* attn_w = (const float*)d_in[4];
    float* out = (float*)d_out;
    const int E = (in_sizes[1] > 0) ? in_sizes[1] : E_DEFAULT;
    const int nblk_s = (E + ECHUNK_S - 1) / ECHUNK_S;     // 196

    char* ws = (char*)d_ws;
    size_t off = 0;
    unsigned short* zbf = (unsigned short*)(ws + off);
    off += (size_t)N_NODES * OUT_DIM * sizeof(unsigned short);       // 6.4 MB
    float* s_l = (float*)(ws + off); off += (size_t)N_NODES * 4;     // 0.4 MB
    float* s_r = (float*)(ws + off); off += (size_t)N_NODES * 4;     // 0.4 MB

    const size_t base = off;
    int* packed = (int*)(ws + off);  off += (size_t)NB * CAP * 4;    // 7.6 MB
    int* cursor = (int*)(ws + off);  off += (size_t)NB * 4;
    const size_t csr_total = off;    // ~14.9 MB
    float* denom = (float*)(ws + base);

    const bool use_csr = (ws_size >= csr_total);

    if (use_csr) {
        k_init_cursor<<<(NB + 255) / 256, 256, 0, stream>>>(cursor);
        const int waves = (N_NODES + 15) / 16;                 // 6250
        const int blocks_z = (waves + 3) / 4;                  // 1563
        k1_mfma<<<blocks_z, 256, 0, stream>>>(h, fc_w, attn_w, zbf, s_l, s_r);
        k_scatter3b<<<nblk_s, 512, 0, stream>>>(src, dst, cursor, packed, E);
        k_bucket_gather<<<NB, 512, 0, stream>>>(cursor, packed, s_l, s_r, zbf, out);
    } else {
        const int blocks_k1 = (N_NODES + 255) / 256;
        k1_z_scores<<<blocks_k1, 256, 0, stream>>>(h, fc_w, attn_w, zbf, s_l, s_r, denom, out);
        const long long tot = (long long)E * 8;
        const int blocks_k3 = (int)((tot + 255) / 256);
        k3_edges<<<blocks_k3, 256, 0, stream>>>(src, dst, s_l, s_r, zbf, denom, out, E);
        const int blocks_k4 = (N_NODES * OUT_DIM + 255) / 256;
        k4_finalize<<<blocks_k4, 256, 0, stream>>>(denom, out);
    }
}

// Round 13
// 166.838 us; speedup vs baseline: 1.7733x; 1.0282x over previous
//
#include <hip/hip_runtime.h>
#include <hip/hip_bf16.h>

#define N_NODES 100000
#define IN_DIM 128
#define OUT_DIM 32
#define NEG_SLOPE 0.01f
#define E_DEFAULT 1600000
#define BUCKET_SHIFT 8
#define BUCKET_SIZE 256
#define NB ((N_NODES + BUCKET_SIZE - 1) / BUCKET_SIZE)   // 391
#define ECHUNK_S 6144    // 261 blocks: all CUs busy; run ~15.7 edges/bin/block
#define CAP 4608         // fixed bucket slot: mean 4092 + 8 sigma (sd ~64)
#define WPAD 136         // bf16 LDS row stride for fc_w

typedef __attribute__((ext_vector_type(8))) short bf16x8;
typedef __attribute__((ext_vector_type(4))) float f32x4;

__device__ __forceinline__ float bfu2f(unsigned int u16) {
    union { unsigned int i; float f; } v;
    v.i = u16 << 16;
    return v.f;
}
__device__ __forceinline__ unsigned short f2bfu(float f) {
    union { unsigned int i; float f; } v;
    v.f = f;
    unsigned int r = v.i + 0x7fffu + ((v.i >> 16) & 1u);  // RNE
    return (unsigned short)(r >> 16);
}

// Init fixed-slot cursors: cursor[bin] = bin*CAP.
__global__ __launch_bounds__(256) void k_init_cursor(int* __restrict__ cursor) {
    const int i = blockIdx.x * 256 + threadIdx.x;
    if (i < NB) cursor[i] = i * CAP;
}

// K1 (MFMA): z = h @ fc_w^T. One wave = 16 nodes x 32 dims, K=128 (r7-proven).
__global__ __launch_bounds__(256) void k1_mfma(
    const float* __restrict__ h,
    const float* __restrict__ fc_w,
    const float* __restrict__ attn_w,
    unsigned short* __restrict__ zbf,
    float* __restrict__ s_l,
    float* __restrict__ s_r) {
    __shared__ unsigned short wlds[OUT_DIM * WPAD];  // 8.5 KB bf16
    __shared__ float al[OUT_DIM], ar[OUT_DIM];

    const int t = threadIdx.x;
    for (int i = t; i < OUT_DIM * IN_DIM / 4; i += 256) {
        const float4 v = ((const float4*)fc_w)[i];
        const int idx = i * 4;
        const int row = idx >> 7, col = idx & 127;
        unsigned short* p = &wlds[row * WPAD + col];
        p[0] = f2bfu(v.x); p[1] = f2bfu(v.y); p[2] = f2bfu(v.z); p[3] = f2bfu(v.w);
    }
    if (t < 2 * OUT_DIM) {
        if (t < OUT_DIM) al[t] = attn_w[t];
        else ar[t - OUT_DIM] = attn_w[t];
    }
    __syncthreads();

    const int wid = blockIdx.x * 4 + (t >> 6);
    int base = wid * 16;
    if (base > N_NODES - 16) base = N_NODES - 16;   // clamp: duplicates benign
    const int lane = t & 63;
    const int row16 = lane & 15;
    const int quad = lane >> 4;

    f32x4 acc0 = {0.f, 0.f, 0.f, 0.f};
    f32x4 acc1 = {0.f, 0.f, 0.f, 0.f};
    const float* hrow = h + (size_t)(base + row16) * IN_DIM + quad * 8;
    const unsigned short* b0 = &wlds[row16 * WPAD + quad * 8];
    const unsigned short* b1 = &wlds[(row16 + 16) * WPAD + quad * 8];

#pragma unroll
    for (int s = 0; s < 4; ++s) {
        const float4 a0 = *(const float4*)(hrow + s * 32);
        const float4 a1 = *(const float4*)(hrow + s * 32 + 4);
        bf16x8 af;
        af[0] = (short)f2bfu(a0.x); af[1] = (short)f2bfu(a0.y);
        af[2] = (short)f2bfu(a0.z); af[3] = (short)f2bfu(a0.w);
        af[4] = (short)f2bfu(a1.x); af[5] = (short)f2bfu(a1.y);
        af[6] = (short)f2bfu(a1.z); af[7] = (short)f2bfu(a1.w);
        const bf16x8 bf0 = *(const bf16x8*)(b0 + s * 32);
        const bf16x8 bf1 = *(const bf16x8*)(b1 + s * 32);
        acc0 = __builtin_amdgcn_mfma_f32_16x16x32_bf16(af, bf0, acc0, 0, 0, 0);
        acc1 = __builtin_amdgcn_mfma_f32_16x16x32_bf16(af, bf1, acc1, 0, 0, 0);
    }

    const float al_lo = al[row16], al_hi = al[row16 + 16];
    const float ar_lo = ar[row16], ar_hi = ar[row16 + 16];
#pragma unroll
    for (int r = 0; r < 4; ++r) {
        const int node = base + quad * 4 + r;
        float p = acc0[r] * al_lo + acc1[r] * al_hi;
        float q = acc0[r] * ar_lo + acc1[r] * ar_hi;
        p += __shfl_xor(p, 1, 64); p += __shfl_xor(p, 2, 64);
        p += __shfl_xor(p, 4, 64); p += __shfl_xor(p, 8, 64);
        q += __shfl_xor(q, 1, 64); q += __shfl_xor(q, 2, 64);
        q += __shfl_xor(q, 4, 64); q += __shfl_xor(q, 8, 64);
        if (row16 == 0) { s_l[node] = p; s_r[node] = q; }
        zbf[(size_t)node * OUT_DIM + row16] = f2bfu(acc0[r]);
        zbf[(size_t)node * OUT_DIM + 16 + row16] = f2bfu(acc1[r]);
    }
}

// Two-pass scatter @6144, 1024 threads: LDS hist -> range reservation from
// fixed-slot cursors -> LDS-cursor placement of packed {ldst:8|src:17}.
__global__ __launch_bounds__(1024) void k_scatter3c(
    const int* __restrict__ src, const int* __restrict__ dst,
    int* __restrict__ cursor, int* __restrict__ packed, int E) {
    __shared__ int bins[NB];
    __shared__ int basep[NB];
    const int t = threadIdx.x;
    if (t < NB) bins[t] = 0;
    __syncthreads();
    const int e0 = blockIdx.x * ECHUNK_S;
#pragma unroll 2
    for (int k = 0; k < ECHUNK_S; k += 1024) {
        const int e = e0 + k + t;
        if (e < E) atomicAdd(&bins[dst[e] >> BUCKET_SHIFT], 1);
    }
    __syncthreads();
    if (t < NB) {
        const int c = bins[t];
        basep[t] = c ? atomicAdd(&cursor[t], c) : 0;
        bins[t] = 0;   // reuse as local cursor
    }
    __syncthreads();
#pragma unroll 2
    for (int k = 0; k < ECHUNK_S; k += 1024) {
        const int e = e0 + k + t;
        if (e < E) {
            const int d = dst[e];
            const int bin = d >> BUCKET_SHIFT;
            const int pos = basep[bin] + atomicAdd(&bins[bin], 1);
            if (pos < (bin + 1) * CAP)   // overflow guard (8-sigma, never fires)
                packed[pos] = ((d & (BUCKET_SIZE - 1)) << 17) | src[e];
        }
    }
}

// One block per 256-node bucket (1024 thr, 16 waves): count (global read),
// LDS scan -> per-node starts, placement (2nd global read; w=exp into LDS),
// then gather: wave = 16 nodes, 8 edge-streams x 8 dim-groups, fused /denom.
__global__ __launch_bounds__(1024) void k_bucket_gather(
    const int* __restrict__ cursor,
    const int* __restrict__ packed,
    const float* __restrict__ s_l,
    const float* __restrict__ s_r,
    const unsigned short* __restrict__ zbf,
    float* __restrict__ out) {
    __shared__ int srcs[CAP];              // 18.4 KB
    __shared__ float wl[CAP];              // 18.4 KB
    __shared__ int cnt256[BUCKET_SIZE];
    __shared__ int pref[BUCKET_SIZE];
    __shared__ int cur[BUCKET_SIZE];
    __shared__ float srt[BUCKET_SIZE];

    const int bin = blockIdx.x;
    const int nbase = bin * BUCKET_SIZE;
    const int pbase = bin * CAP;
    const int t = threadIdx.x;
    int cnt = cursor[bin] - pbase;
    if (cnt > CAP) cnt = CAP;
    if (cnt < 0) cnt = 0;

    if (t < BUCKET_SIZE) {
        cnt256[t] = 0;
        const int n = nbase + t;
        srt[t] = (n < N_NODES) ? s_r[n] : 0.f;
    }
    __syncthreads();
    for (int i = t; i < cnt; i += 1024) {
        atomicAdd(&cnt256[packed[pbase + i] >> 17], 1);
    }
    __syncthreads();
    if (t < BUCKET_SIZE) pref[t] = cnt256[t];
    __syncthreads();
    for (int off = 1; off < BUCKET_SIZE; off <<= 1) {
        int u = 0;
        if (t < BUCKET_SIZE && t >= off) u = pref[t - off];
        __syncthreads();
        if (t < BUCKET_SIZE) pref[t] += u;
        __syncthreads();
    }
    if (t < BUCKET_SIZE) cur[t] = pref[t] - cnt256[t];   // exclusive start
    __syncthreads();
    for (int i = t; i < cnt; i += 1024) {
        const int p = packed[pbase + i];    // L2-hit re-read
        const int ldst = p >> 17;
        const int sn = p & 0x1FFFF;
        const int pos = atomicAdd(&cur[ldst], 1);
        float x = s_l[sn] + srt[ldst];
        x = (x > 0.f) ? x : NEG_SLOPE * x;
        srcs[pos] = sn;
        wl[pos] = __expf(x);
    }
    __syncthreads();

    const int wv = t >> 6;          // 16 waves
    const int lane = t & 63;
    const int eslot = lane >> 3;    // 8 edge streams
    const int dimg = lane & 7;      // 8 dim groups x 4 dims
#pragma unroll 2
    for (int j = 0; j < 16; ++j) {
        const int ln = wv * 16 + j;
        const int st = pref[ln] - cnt256[ln];
        const int ce = pref[ln];
        float a0 = 0.f, a1 = 0.f, a2 = 0.f, a3 = 0.f, dn = 0.f;
        for (int i = st + eslot; i < ce; i += 8) {
            const int es = srcs[i];
            const float w = wl[i];
            const uint2 zv = *(const uint2*)&zbf[(size_t)es * OUT_DIM + dimg * 4];
            a0 += w * bfu2f(zv.x & 0xffffu);
            a1 += w * bfu2f(zv.x >> 16);
            a2 += w * bfu2f(zv.y & 0xffffu);
            a3 += w * bfu2f(zv.y >> 16);
            dn += w;
        }
#pragma unroll
        for (int m = 8; m < 64; m <<= 1) {
            a0 += __shfl_xor(a0, m, 64);
            a1 += __shfl_xor(a1, m, 64);
            a2 += __shfl_xor(a2, m, 64);
            a3 += __shfl_xor(a3, m, 64);
            dn += __shfl_xor(dn, m, 64);
        }
        const int n = nbase + ln;
        if (eslot == 0 && n < N_NODES) {
            const float inv = (dn > 0.f) ? 1.f / dn : 0.f;
            *(float4*)&out[(size_t)n * OUT_DIM + dimg * 4] =
                make_float4(a0 * inv, a1 * inv, a2 * inv, a3 * inv);
        }
    }
}

// ---------------- atomic fallback path (known-passing) ----------

__global__ __launch_bounds__(256) void k1_z_scores(
    const float* __restrict__ h,
    const float* __restrict__ fc_w,
    const float* __restrict__ attn_w,
    unsigned short* __restrict__ zbf,
    float* __restrict__ s_l,
    float* __restrict__ s_r,
    float* __restrict__ denom,
    float* __restrict__ out) {
    __shared__ float wlds[OUT_DIM * IN_DIM];
    __shared__ float al[OUT_DIM], ar[OUT_DIM];

    const int tid = threadIdx.x;
    for (int i = tid; i < OUT_DIM * IN_DIM; i += 256) wlds[i] = fc_w[i];
    if (tid < OUT_DIM) {
        al[tid] = attn_w[tid];
        ar[tid] = attn_w[OUT_DIM + tid];
    }
    __syncthreads();

    const int node = blockIdx.x * 256 + tid;
    if (node >= N_NODES) return;

    float acc[OUT_DIM];
#pragma unroll
    for (int j = 0; j < OUT_DIM; ++j) acc[j] = 0.f;
    const float4* hp = (const float4*)(h + (size_t)node * IN_DIM);
#pragma unroll 4
    for (int kg = 0; kg < IN_DIM / 4; ++kg) {
        const float4 hv = hp[kg];
#pragma unroll
        for (int j = 0; j < OUT_DIM; ++j) {
            const float4 w = *(const float4*)&wlds[j * IN_DIM + kg * 4];
            acc[j] += hv.x * w.x + hv.y * w.y + hv.z * w.z + hv.w * w.w;
        }
    }
    float sl = 0.f, sr = 0.f;
#pragma unroll
    for (int j = 0; j < OUT_DIM; ++j) { sl += acc[j] * al[j]; sr += acc[j] * ar[j]; }
    s_l[node] = sl; s_r[node] = sr; denom[node] = 0.f;
    uint4* zp = (uint4*)(zbf + (size_t)node * OUT_DIM);
#pragma unroll
    for (int q = 0; q < 4; ++q) {
        uint4 pk;
        pk.x = (unsigned int)f2bfu(acc[8 * q + 0]) | ((unsigned int)f2bfu(acc[8 * q + 1]) << 16);
        pk.y = (unsigned int)f2bfu(acc[8 * q + 2]) | ((unsigned int)f2bfu(acc[8 * q + 3]) << 16);
        pk.z = (unsigned int)f2bfu(acc[8 * q + 4]) | ((unsigned int)f2bfu(acc[8 * q + 5]) << 16);
        pk.w = (unsigned int)f2bfu(acc[8 * q + 6]) | ((unsigned int)f2bfu(acc[8 * q + 7]) << 16);
        zp[q] = pk;
    }
    float4* op = (float4*)(out + (size_t)node * OUT_DIM);
    const float4 zero4 = make_float4(0.f, 0.f, 0.f, 0.f);
#pragma unroll
    for (int q = 0; q < 8; ++q) op[q] = zero4;
}

__global__ __launch_bounds__(256) void k3_edges(
    const int* __restrict__ src, const int* __restrict__ dst,
    const float* __restrict__ s_l, const float* __restrict__ s_r,
    const unsigned short* __restrict__ zbf,
    float* __restrict__ denom, float* __restrict__ out, int E) {
    const long long gid = (long long)blockIdx.x * 256 + threadIdx.x;
    const int e = (int)(gid >> 3);
    const int q = (int)(gid & 7);
    if (e >= E) return;
    const int s = src[e];
    const int d = dst[e];
    float x = s_l[s] + s_r[d];
    x = (x > 0.f) ? x : NEG_SLOPE * x;
    const float w = __expf(x);
    const uint2 zv = *(const uint2*)&zbf[(size_t)s * OUT_DIM + q * 4];
    float* op = &out[(size_t)d * OUT_DIM + q * 4];
    unsafeAtomicAdd(op + 0, w * bfu2f(zv.x & 0xffffu));
    unsafeAtomicAdd(op + 1, w * bfu2f(zv.x >> 16));
    unsafeAtomicAdd(op + 2, w * bfu2f(zv.y & 0xffffu));
    unsafeAtomicAdd(op + 3, w * bfu2f(zv.y >> 16));
    if (q == 0) unsafeAtomicAdd(&denom[d], w);
}

__global__ __launch_bounds__(256) void k4_finalize(
    const float* __restrict__ denom, float* __restrict__ out) {
    const int i = blockIdx.x * 256 + threadIdx.x;
    if (i >= N_NODES * OUT_DIM) return;
    const float dnm = denom[i >> 5];
    out[i] = (dnm > 0.f) ? out[i] / dnm : 0.f;
}

extern "C" void kernel_launch(void* const* d_in, const int* in_sizes, int n_in,
                              void* d_out, int out_size, void* d_ws, size_t ws_size,
                              hipStream_t stream) {
    const float* h      = (const float*)d_in[0];
    const int*   src    = (const int*)d_in[1];
    const int*   dst    = (const int*)d_in[2];
    const float* fc_w   = (const float*)d_in[3];
    const float* attn_w = (const float*)d_in[4];
    float* out = (float*)d_out;
    const int E = (in_sizes[1] > 0) ? in_sizes[1] : E_DEFAULT;
    const int nblk_s = (E + ECHUNK_S - 1) / ECHUNK_S;     // 261

    char* ws = (char*)d_ws;
    size_t off = 0;
    unsigned short* zbf = (unsigned short*)(ws + off);
    off += (size_t)N_NODES * OUT_DIM * sizeof(unsigned short);       // 6.4 MB
    float* s_l = (float*)(ws + off); off += (size_t)N_NODES * 4;     // 0.4 MB
    float* s_r = (float*)(ws + off); off += (size_t)N_NODES * 4;     // 0.4 MB

    const size_t base = off;
    int* packed = (int*)(ws + off);  off += (size_t)NB * CAP * 4;    // 7.2 MB
    int* cursor = (int*)(ws + off);  off += (size_t)NB * 4;
    const size_t csr_total = off;    // ~14.4 MB
    float* denom = (float*)(ws + base);

    const bool use_csr = (ws_size >= csr_total);

    if (use_csr) {
        k_init_cursor<<<(NB + 255) / 256, 256, 0, stream>>>(cursor);
        const int waves = (N_NODES + 15) / 16;                 // 6250
        const int blocks_z = (waves + 3) / 4;                  // 1563
        k1_mfma<<<blocks_z, 256, 0, stream>>>(h, fc_w, attn_w, zbf, s_l, s_r);
        k_scatter3c<<<nblk_s, 1024, 0, stream>>>(src, dst, cursor, packed, E);
        k_bucket_gather<<<NB, 1024, 0, stream>>>(cursor, packed, s_l, s_r, zbf, out);
    } else {
        const int blocks_k1 = (N_NODES + 255) / 256;
        k1_z_scores<<<blocks_k1, 256, 0, stream>>>(h, fc_w, attn_w, zbf, s_l, s_r, denom, out);
        const long long tot = (long long)E * 8;
        const int blocks_k3 = (int)((tot + 255) / 256);
        k3_edges<<<blocks_k3, 256, 0, stream>>>(src, dst, s_l, s_r, zbf, denom, out, E);
        const int blocks_k4 = (N_NODES * OUT_DIM + 255) / 256;
        k4_finalize<<<blocks_k4, 256, 0, stream>>>(denom, out);
    }
}

// Round 14
// 165.248 us; speedup vs baseline: 1.7904x; 1.0096x over previous
//
#include <hip/hip_runtime.h>
#include <hip/hip_bf16.h>

#define N_NODES 100000
#define IN_DIM 128
#define OUT_DIM 32
#define NEG_SLOPE 0.01f
#define E_DEFAULT 1600000
#define BUCKET_SHIFT 8
#define BUCKET_SIZE 256
#define NB ((N_NODES + BUCKET_SIZE - 1) / BUCKET_SIZE)   // 391
#define ECHUNK_S 6144    // 261 blocks; run ~15.7 edges/bin/block (measured)
#define CAP 4608         // fixed bucket slot: mean 4092 + 8 sigma (sd ~64)
#define WPAD 136         // bf16 LDS row stride for fc_w

typedef __attribute__((ext_vector_type(8))) short bf16x8;
typedef __attribute__((ext_vector_type(4))) float f32x4;

__device__ __forceinline__ float bfu2f(unsigned int u16) {
    union { unsigned int i; float f; } v;
    v.i = u16 << 16;
    return v.f;
}
__device__ __forceinline__ unsigned short f2bfu(float f) {
    union { unsigned int i; float f; } v;
    v.f = f;
    unsigned int r = v.i + 0x7fffu + ((v.i >> 16) & 1u);  // RNE
    return (unsigned short)(r >> 16);
}

// K1 (MFMA): z = h @ fc_w^T. One wave = 32 nodes (2 M-tiles) x 32 dims,
// K=128. 16 independent h-loads in flight per wave. Block 0 also inits the
// fixed-slot cursors (k1 precedes scatter in stream order).
__global__ __launch_bounds__(256) void k1_mfma2(
    const float* __restrict__ h,
    const float* __restrict__ fc_w,
    const float* __restrict__ attn_w,
    unsigned short* __restrict__ zbf,
    float* __restrict__ s_l,
    float* __restrict__ s_r,
    int* __restrict__ cursor) {
    __shared__ unsigned short wlds[OUT_DIM * WPAD];  // 8.5 KB bf16
    __shared__ float al[OUT_DIM], ar[OUT_DIM];

    const int t = threadIdx.x;
    if (blockIdx.x == 0) {
        for (int i = t; i < NB; i += 256) cursor[i] = i * CAP;
    }
    for (int i = t; i < OUT_DIM * IN_DIM / 4; i += 256) {
        const float4 v = ((const float4*)fc_w)[i];
        const int idx = i * 4;
        const int row = idx >> 7, col = idx & 127;
        unsigned short* p = &wlds[row * WPAD + col];
        p[0] = f2bfu(v.x); p[1] = f2bfu(v.y); p[2] = f2bfu(v.z); p[3] = f2bfu(v.w);
    }
    if (t < 2 * OUT_DIM) {
        if (t < OUT_DIM) al[t] = attn_w[t];
        else ar[t - OUT_DIM] = attn_w[t];
    }
    __syncthreads();

    const int wid = blockIdx.x * 4 + (t >> 6);
    int base = wid * 32;
    if (base > N_NODES - 32) base = N_NODES - 32;   // clamp: duplicates benign
    const int lane = t & 63;
    const int row16 = lane & 15;
    const int quad = lane >> 4;

    f32x4 accA0 = {0.f, 0.f, 0.f, 0.f};   // tile A (nodes base..base+15)
    f32x4 accA1 = {0.f, 0.f, 0.f, 0.f};
    f32x4 accB0 = {0.f, 0.f, 0.f, 0.f};   // tile B (nodes base+16..base+31)
    f32x4 accB1 = {0.f, 0.f, 0.f, 0.f};
    const float* hrowA = h + (size_t)(base + row16) * IN_DIM + quad * 8;
    const float* hrowB = h + (size_t)(base + 16 + row16) * IN_DIM + quad * 8;
    const unsigned short* b0 = &wlds[row16 * WPAD + quad * 8];
    const unsigned short* b1 = &wlds[(row16 + 16) * WPAD + quad * 8];

#pragma unroll
    for (int s = 0; s < 4; ++s) {
        const float4 a0 = *(const float4*)(hrowA + s * 32);
        const float4 a1 = *(const float4*)(hrowA + s * 32 + 4);
        const float4 c0 = *(const float4*)(hrowB + s * 32);
        const float4 c1 = *(const float4*)(hrowB + s * 32 + 4);
        bf16x8 afA, afB;
        afA[0] = (short)f2bfu(a0.x); afA[1] = (short)f2bfu(a0.y);
        afA[2] = (short)f2bfu(a0.z); afA[3] = (short)f2bfu(a0.w);
        afA[4] = (short)f2bfu(a1.x); afA[5] = (short)f2bfu(a1.y);
        afA[6] = (short)f2bfu(a1.z); afA[7] = (short)f2bfu(a1.w);
        afB[0] = (short)f2bfu(c0.x); afB[1] = (short)f2bfu(c0.y);
        afB[2] = (short)f2bfu(c0.z); afB[3] = (short)f2bfu(c0.w);
        afB[4] = (short)f2bfu(c1.x); afB[5] = (short)f2bfu(c1.y);
        afB[6] = (short)f2bfu(c1.z); afB[7] = (short)f2bfu(c1.w);
        const bf16x8 bf0 = *(const bf16x8*)(b0 + s * 32);
        const bf16x8 bf1 = *(const bf16x8*)(b1 + s * 32);
        accA0 = __builtin_amdgcn_mfma_f32_16x16x32_bf16(afA, bf0, accA0, 0, 0, 0);
        accA1 = __builtin_amdgcn_mfma_f32_16x16x32_bf16(afA, bf1, accA1, 0, 0, 0);
        accB0 = __builtin_amdgcn_mfma_f32_16x16x32_bf16(afB, bf0, accB0, 0, 0, 0);
        accB1 = __builtin_amdgcn_mfma_f32_16x16x32_bf16(afB, bf1, accB1, 0, 0, 0);
    }

    const float al_lo = al[row16], al_hi = al[row16 + 16];
    const float ar_lo = ar[row16], ar_hi = ar[row16 + 16];
#pragma unroll
    for (int tile = 0; tile < 2; ++tile) {
        const f32x4 d0 = tile ? accB0 : accA0;
        const f32x4 d1 = tile ? accB1 : accA1;
        const int tb = base + tile * 16;
#pragma unroll
        for (int r = 0; r < 4; ++r) {
            const int node = tb + quad * 4 + r;
            float p = d0[r] * al_lo + d1[r] * al_hi;
            float q = d0[r] * ar_lo + d1[r] * ar_hi;
            p += __shfl_xor(p, 1, 64); p += __shfl_xor(p, 2, 64);
            p += __shfl_xor(p, 4, 64); p += __shfl_xor(p, 8, 64);
            q += __shfl_xor(q, 1, 64); q += __shfl_xor(q, 2, 64);
            q += __shfl_xor(q, 4, 64); q += __shfl_xor(q, 8, 64);
            if (row16 == 0) { s_l[node] = p; s_r[node] = q; }
            zbf[(size_t)node * OUT_DIM + row16] = f2bfu(d0[r]);
            zbf[(size_t)node * OUT_DIM + 16 + row16] = f2bfu(d1[r]);
        }
    }
}

// Two-pass scatter @6144, 1024 threads: LDS hist -> range reservation from
// fixed-slot cursors -> LDS-cursor placement of packed {ldst:8|src:17}.
__global__ __launch_bounds__(1024) void k_scatter3c(
    const int* __restrict__ src, const int* __restrict__ dst,
    int* __restrict__ cursor, int* __restrict__ packed, int E) {
    __shared__ int bins[NB];
    __shared__ int basep[NB];
    const int t = threadIdx.x;
    if (t < NB) bins[t] = 0;
    __syncthreads();
    const int e0 = blockIdx.x * ECHUNK_S;
#pragma unroll 2
    for (int k = 0; k < ECHUNK_S; k += 1024) {
        const int e = e0 + k + t;
        if (e < E) atomicAdd(&bins[dst[e] >> BUCKET_SHIFT], 1);
    }
    __syncthreads();
    if (t < NB) {
        const int c = bins[t];
        basep[t] = c ? atomicAdd(&cursor[t], c) : 0;
        bins[t] = 0;   // reuse as local cursor
    }
    __syncthreads();
#pragma unroll 2
    for (int k = 0; k < ECHUNK_S; k += 1024) {
        const int e = e0 + k + t;
        if (e < E) {
            const int d = dst[e];
            const int bin = d >> BUCKET_SHIFT;
            const int pos = basep[bin] + atomicAdd(&bins[bin], 1);
            if (pos < (bin + 1) * CAP)   // overflow guard (8-sigma, never fires)
                packed[pos] = ((d & (BUCKET_SIZE - 1)) << 17) | src[e];
        }
    }
}

// One block per 256-node bucket (1024 thr, 16 waves): count (global read),
// LDS scan -> per-node starts, placement (2nd global read; w=exp into LDS),
// then gather: wave = 16 nodes, 8 edge-streams x 8 dim-groups, fused /denom.
__global__ __launch_bounds__(1024) void k_bucket_gather(
    const int* __restrict__ cursor,
    const int* __restrict__ packed,
    const float* __restrict__ s_l,
    const float* __restrict__ s_r,
    const unsigned short* __restrict__ zbf,
    float* __restrict__ out) {
    __shared__ int srcs[CAP];              // 18.4 KB
    __shared__ float wl[CAP];              // 18.4 KB
    __shared__ int cnt256[BUCKET_SIZE];
    __shared__ int pref[BUCKET_SIZE];
    __shared__ int cur[BUCKET_SIZE];
    __shared__ float srt[BUCKET_SIZE];

    const int bin = blockIdx.x;
    const int nbase = bin * BUCKET_SIZE;
    const int pbase = bin * CAP;
    const int t = threadIdx.x;
    int cnt = cursor[bin] - pbase;
    if (cnt > CAP) cnt = CAP;
    if (cnt < 0) cnt = 0;

    if (t < BUCKET_SIZE) {
        cnt256[t] = 0;
        const int n = nbase + t;
        srt[t] = (n < N_NODES) ? s_r[n] : 0.f;
    }
    __syncthreads();
    for (int i = t; i < cnt; i += 1024) {
        atomicAdd(&cnt256[packed[pbase + i] >> 17], 1);
    }
    __syncthreads();
    if (t < BUCKET_SIZE) pref[t] = cnt256[t];
    __syncthreads();
    for (int off = 1; off < BUCKET_SIZE; off <<= 1) {
        int u = 0;
        if (t < BUCKET_SIZE && t >= off) u = pref[t - off];
        __syncthreads();
        if (t < BUCKET_SIZE) pref[t] += u;
        __syncthreads();
    }
    if (t < BUCKET_SIZE) cur[t] = pref[t] - cnt256[t];   // exclusive start
    __syncthreads();
    for (int i = t; i < cnt; i += 1024) {
        const int p = packed[pbase + i];    // L2-hit re-read
        const int ldst = p >> 17;
        const int sn = p & 0x1FFFF;
        const int pos = atomicAdd(&cur[ldst], 1);
        float x = s_l[sn] + srt[ldst];
        x = (x > 0.f) ? x : NEG_SLOPE * x;
        srcs[pos] = sn;
        wl[pos] = __expf(x);
    }
    __syncthreads();

    const int wv = t >> 6;          // 16 waves
    const int lane = t & 63;
    const int eslot = lane >> 3;    // 8 edge streams
    const int dimg = lane & 7;      // 8 dim groups x 4 dims
#pragma unroll 2
    for (int j = 0; j < 16; ++j) {
        const int ln = wv * 16 + j;
        const int st = pref[ln] - cnt256[ln];
        const int ce = pref[ln];
        float a0 = 0.f, a1 = 0.f, a2 = 0.f, a3 = 0.f, dn = 0.f;
        for (int i = st + eslot; i < ce; i += 8) {
            const int es = srcs[i];
            const float w = wl[i];
            const uint2 zv = *(const uint2*)&zbf[(size_t)es * OUT_DIM + dimg * 4];
            a0 += w * bfu2f(zv.x & 0xffffu);
            a1 += w * bfu2f(zv.x >> 16);
            a2 += w * bfu2f(zv.y & 0xffffu);
            a3 += w * bfu2f(zv.y >> 16);
            dn += w;
        }
#pragma unroll
        for (int m = 8; m < 64; m <<= 1) {
            a0 += __shfl_xor(a0, m, 64);
            a1 += __shfl_xor(a1, m, 64);
            a2 += __shfl_xor(a2, m, 64);
            a3 += __shfl_xor(a3, m, 64);
            dn += __shfl_xor(dn, m, 64);
        }
        const int n = nbase + ln;
        if (eslot == 0 && n < N_NODES) {
            const float inv = (dn > 0.f) ? 1.f / dn : 0.f;
            *(float4*)&out[(size_t)n * OUT_DIM + dimg * 4] =
                make_float4(a0 * inv, a1 * inv, a2 * inv, a3 * inv);
        }
    }
}

// ---------------- atomic fallback path (known-passing) ----------

__global__ __launch_bounds__(256) void k1_z_scores(
    const float* __restrict__ h,
    const float* __restrict__ fc_w,
    const float* __restrict__ attn_w,
    unsigned short* __restrict__ zbf,
    float* __restrict__ s_l,
    float* __restrict__ s_r,
    float* __restrict__ denom,
    float* __restrict__ out) {
    __shared__ float wlds[OUT_DIM * IN_DIM];
    __shared__ float al[OUT_DIM], ar[OUT_DIM];

    const int tid = threadIdx.x;
    for (int i = tid; i < OUT_DIM * IN_DIM; i += 256) wlds[i] = fc_w[i];
    if (tid < OUT_DIM) {
        al[tid] = attn_w[tid];
        ar[tid] = attn_w[OUT_DIM + tid];
    }
    __syncthreads();

    const int node = blockIdx.x * 256 + tid;
    if (node >= N_NODES) return;

    float acc[OUT_DIM];
#pragma unroll
    for (int j = 0; j < OUT_DIM; ++j) acc[j] = 0.f;
    const float4* hp = (const float4*)(h + (size_t)node * IN_DIM);
#pragma unroll 4
    for (int kg = 0; kg < IN_DIM / 4; ++kg) {
        const float4 hv = hp[kg];
#pragma unroll
        for (int j = 0; j < OUT_DIM; ++j) {
            const float4 w = *(const float4*)&wlds[j * IN_DIM + kg * 4];
            acc[j] += hv.x * w.x + hv.y * w.y + hv.z * w.z + hv.w * w.w;
        }
    }
    float sl = 0.f, sr = 0.f;
#pragma unroll
    for (int j = 0; j < OUT_DIM; ++j) { sl += acc[j] * al[j]; sr += acc[j] * ar[j]; }
    s_l[node] = sl; s_r[node] = sr; denom[node] = 0.f;
    uint4* zp = (uint4*)(zbf + (size_t)node * OUT_DIM);
#pragma unroll
    for (int q = 0; q < 4; ++q) {
        uint4 pk;
        pk.x = (unsigned int)f2bfu(acc[8 * q + 0]) | ((unsigned int)f2bfu(acc[8 * q + 1]) << 16);
        pk.y = (unsigned int)f2bfu(acc[8 * q + 2]) | ((unsigned int)f2bfu(acc[8 * q + 3]) << 16);
        pk.z = (unsigned int)f2bfu(acc[8 * q + 4]) | ((unsigned int)f2bfu(acc[8 * q + 5]) << 16);
        pk.w = (unsigned int)f2bfu(acc[8 * q + 6]) | ((unsigned int)f2bfu(acc[8 * q + 7]) << 16);
        zp[q] = pk;
    }
    float4* op = (float4*)(out + (size_t)node * OUT_DIM);
    const float4 zero4 = make_float4(0.f, 0.f, 0.f, 0.f);
#pragma unroll
    for (int q = 0; q < 8; ++q) op[q] = zero4;
}

__global__ __launch_bounds__(256) void k3_edges(
    const int* __restrict__ src, const int* __restrict__ dst,
    const float* __restrict__ s_l, const float* __restrict__ s_r,
    const unsigned short* __restrict__ zbf,
    float* __restrict__ denom, float* __restrict__ out, int E) {
    const long long gid = (long long)blockIdx.x * 256 + threadIdx.x;
    const int e = (int)(gid >> 3);
    const int q = (int)(gid & 7);
    if (e >= E) return;
    const int s = src[e];
    const int d = dst[e];
    float x = s_l[s] + s_r[d];
    x = (x > 0.f) ? x : NEG_SLOPE * x;
    const float w = __expf(x);
    const uint2 zv = *(const uint2*)&zbf[(size_t)s * OUT_DIM + q * 4];
    float* op = &out[(size_t)d * OUT_DIM + q * 4];
    unsafeAtomicAdd(op + 0, w * bfu2f(zv.x & 0xffffu));
    unsafeAtomicAdd(op + 1, w * bfu2f(zv.x >> 16));
    unsafeAtomicAdd(op + 2, w * bfu2f(zv.y & 0xffffu));
    unsafeAtomicAdd(op + 3, w * bfu2f(zv.y >> 16));
    if (q == 0) unsafeAtomicAdd(&denom[d], w);
}

__global__ __launch_bounds__(256) void k4_finalize(
    const float* __restrict__ denom, float* __restrict__ out) {
    const int i = blockIdx.x * 256 + threadIdx.x;
    if (i >= N_NODES * OUT_DIM) return;
    const float dnm = denom[i >> 5];
    out[i] = (dnm > 0.f) ? out[i] / dnm : 0.f;
}

extern "C" void kernel_launch(void* const* d_in, const int* in_sizes, int n_in,
                              void* d_out, int out_size, void* d_ws, size_t ws_size,
                              hipStream_t stream) {
    const float* h      = (const float*)d_in[0];
    const int*   src    = (const int*)d_in[1];
    const int*   dst    = (const int*)d_in[2];
    const float* fc_w   = (const float*)d_in[3];
    const float* attn_w = (const float*)d_in[4];
    float* out = (float*)d_out;
    const int E = (in_sizes[1] > 0) ? in_sizes[1] : E_DEFAULT;
    const int nblk_s = (E + ECHUNK_S - 1) / ECHUNK_S;     // 261

    char* ws = (char*)d_ws;
    size_t off = 0;
    unsigned short* zbf = (unsigned short*)(ws + off);
    off += (size_t)N_NODES * OUT_DIM * sizeof(unsigned short);       // 6.4 MB
    float* s_l = (float*)(ws + off); off += (size_t)N_NODES * 4;     // 0.4 MB
    float* s_r = (float*)(ws + off); off += (size_t)N_NODES * 4;     // 0.4 MB

    const size_t base = off;
    int* packed = (int*)(ws + off);  off += (size_t)NB * CAP * 4;    // 7.2 MB
    int* cursor = (int*)(ws + off);  off += (size_t)NB * 4;
    const size_t csr_total = off;    // ~14.4 MB
    float* denom = (float*)(ws + base);

    const bool use_csr = (ws_size >= csr_total);

    if (use_csr) {
        const int waves = (N_NODES + 31) / 32;                 // 3125
        const int blocks_z = (waves + 3) / 4;                  // 782
        k1_mfma2<<<blocks_z, 256, 0, stream>>>(h, fc_w, attn_w, zbf, s_l, s_r, cursor);
        k_scatter3c<<<nblk_s, 1024, 0, stream>>>(src, dst, cursor, packed, E);
        k_bucket_gather<<<NB, 1024, 0, stream>>>(cursor, packed, s_l, s_r, zbf, out);
    } else {
        const int blocks_k1 = (N_NODES + 255) / 256;
        k1_z_scores<<<blocks_k1, 256, 0, stream>>>(h, fc_w, attn_w, zbf, s_l, s_r, denom, out);
        const long long tot = (long long)E * 8;
        const int blocks_k3 = (int)((tot + 255) / 256);
        k3_edges<<<blocks_k3, 256, 0, stream>>>(src, dst, s_l, s_r, zbf, denom, out, E);
        const int blocks_k4 = (N_NODES * OUT_DIM + 255) / 256;
        k4_finalize<<<blocks_k4, 256, 0, stream>>>(denom, out);
    }
}